// Round 7
// baseline (33.541 us; speedup 1.0000x reference)
//
#include <hip/hip_runtime.h>
#include <math.h>

typedef float v2f __attribute__((ext_vector_type(2)));

#define Bb 8
#define Nn 4096
#define Mm 4096
#define QP 8                    // query points per thread (registers)
#define WAVES 8                 // waves per block
#define BLOCK (WAVES * 64)      // 512 threads
#define NE 8                    // M split into eighths
#define ME (Mm / NE)            // 512 targets per eighth
#define PAIRS (ME / 2)          // 256 target pairs (pair-transposed in LDS)
#define SLICEP (PAIRS / WAVES)  // 32 pairs per wave
#define QTILES (Nn / (64 * QP)) // 8 query tiles per (dir,b)
#define NQ (2 * Bb * Nn)        // 65536 query slots (both dirs)

// packed-f32 FMA with src0 word-broadcast (compile-time op_sel):
//   pk_fma_b0: d.{lo,hi} = a.lo * b.{lo,hi} + c.{lo,hi}
//   pk_fma_b1: d.{lo,hi} = a.hi * b.{lo,hi} + c.{lo,hi}
__device__ __forceinline__ v2f pk_fma_b0(v2f a, v2f b, v2f c) {
    v2f d;
    asm("v_pk_fma_f32 %0, %1, %2, %3 op_sel_hi:[0,1,1]"
        : "=v"(d) : "v"(a), "v"(b), "v"(c));
    return d;
}
__device__ __forceinline__ v2f pk_fma_b1(v2f a, v2f b, v2f c) {
    v2f d;
    asm("v_pk_fma_f32 %0, %1, %2, %3 op_sel:[1,0,0] op_sel_hi:[1,1,1]"
        : "=v"(d) : "v"(a), "v"(b), "v"(c));
    return d;
}

// d_ws layout:
//   mins[NQ][NE]     : per-query per-eighth partial (pp + min_eighth), 2 MB
//   partials[128][4] : per-reduce-block {chamferA, emd, chamferB, unc} sums
// Every slot rewritten every call (no memset, no atomics, deterministic).

// grid = 2 dirs x 8 batches x 8 qtiles x 8 eighths = 1024 blocks of 512 thr.
// QP=8 keeps per-thread state ~60 VGPR -> 8 waves/SIMD (4 blocks/CU, 64 KB
// LDS) for full latency hiding. |p|^2 is NOT kept live through the main
// loop; it is recomputed in the epilogue from {-2x,-2y,-2z} with static q.
__global__ void __launch_bounds__(BLOCK) chamfer_kernel(
    const float* __restrict__ pred,
    const float* __restrict__ targ,
    float* __restrict__ mins)
{
    // union: target stage (2*PAIRS+2 float4) reused as smin[QP][WAVES][64]
    __shared__ float4 shbuf[QP * WAVES * 16];   // 16 KB
    float4* ts   = shbuf;
    float*  smin = (float*)shbuf;

    const int tid  = threadIdx.x;
    const int lane = tid & 63;
    const int wave = tid >> 6;

    const int id     = blockIdx.x;
    const int eighth = id & (NE - 1);
    const int tile   = (id >> 3) & (QTILES - 1);
    const int b      = (id >> 6) & (Bb - 1);
    const int dir    = id >> 9;

    const float* Q = dir ? targ : pred;
    const float* T = dir ? pred : targ;

    // ---- stage this M-eighth, pair-transposed {x0,x1,y0,y1},{z0,z1,w0,w1} ----
    if (tid < PAIRS) {
        const float2* g2 = (const float2*)(T + ((size_t)b * Mm + eighth * ME + 2 * tid) * 3);
        float2 f01 = g2[0], f23 = g2[1], f45 = g2[2];
        float x0 = f01.x, y0 = f01.y, z0 = f23.x;
        float x1 = f23.y, y1 = f45.x, z1 = f45.y;
        float w0 = fmaf(x0, x0, fmaf(y0, y0, z0 * z0));
        float w1 = fmaf(x1, x1, fmaf(y1, y1, z1 * z1));
        ts[2 * tid]     = make_float4(x0, x1, y0, y1);
        ts[2 * tid + 1] = make_float4(z0, z1, w0, w1);
    }

    // ---- this thread's QP query points: qxy={-2x,-2y}, qzz packs -2z pairs ----
    v2f qxy[QP], qzz[QP / 2];
    float mn[QP];
    #pragma unroll
    for (int q = 0; q < QP; ++q) {
        const int n = tile * (64 * QP) + q * 64 + lane;
        const float* g = Q + ((size_t)b * Nn + n) * 3;
        float x = g[0], y = g[1], z = g[2];
        qxy[q][0] = -2.0f * x;  qxy[q][1] = -2.0f * y;
        qzz[q >> 1][q & 1] = -2.0f * z;
        mn[q] = __builtin_inff();
    }

    __syncthreads();

    // ---- main loop: 1 target-pair/iter; 2 instr per (q, target) ----
    const float4* tw = ts + wave * (SLICEP * 2);
    for (int m = 0; m < SLICEP; ++m) {
        float4 c0 = tw[2 * m], c1 = tw[2 * m + 1];
        v2f xx = {c0.x, c0.y}, yy = {c0.z, c0.w};
        v2f zz = {c1.x, c1.y}, ww = {c1.z, c1.w};
        #pragma unroll
        for (int q = 0; q < QP; ++q) {
            v2f d0 = (q & 1) ? pk_fma_b1(qzz[q >> 1], zz, ww)
                             : pk_fma_b0(qzz[q >> 1], zz, ww);
            v2f d1 = pk_fma_b1(qxy[q], yy, d0);
            v2f d2 = pk_fma_b0(qxy[q], xx, d1);
            mn[q] = fminf(fminf(mn[q], d2[0]), d2[1]);   // -> v_min3_f32
        }
    }

    // ---- epilogue: recompute |p|^2 (static q), fold into smin write ----
    __syncthreads();                    // done reading ts -> reuse as smin
    #pragma unroll
    for (int q = 0; q < QP; ++q) {
        const float tx = qxy[q][0], ty = qxy[q][1], tz = qzz[q >> 1][q & 1];
        const float pp = 0.25f * fmaf(tx, tx, fmaf(ty, ty, tz * tz));
        smin[(q * WAVES + wave) * 64 + lane] = mn[q] + pp;
    }
    __syncthreads();

    // ---- cross-wave min: wave w reduces q == w (QP == WAVES) ----
    {
        const int q = wave;
        float v = smin[(q * WAVES + 0) * 64 + lane];
        #pragma unroll
        for (int w = 1; w < WAVES; ++w)
            v = fminf(v, smin[(q * WAVES + w) * 64 + lane]);
        const int n = tile * (64 * QP) + q * 64 + lane;
        const size_t qg = ((size_t)dir * Bb + b) * Nn + n;
        mins[qg * NE + eighth] = v;
    }
}

// 128 blocks x 256 thr: min over NE eighths, per-block partial sums (no atomics)
__global__ void __launch_bounds__(256) reduce_kernel(
    const float* __restrict__ mins, const float* __restrict__ unc,
    float* __restrict__ partials)
{
    const int q = blockIdx.x * 256 + threadIdx.x;    // [0, 32768)
    const float4* m4 = (const float4*)mins;          // 2 float4 per query

    float4 a0 = m4[2 * q],           a1 = m4[2 * q + 1];
    float4 b0 = m4[2 * (q + 32768)], b1 = m4[2 * (q + 32768) + 1];
    float vA = fminf(fminf(fminf(a0.x, a0.y), fminf(a0.z, a0.w)),
                     fminf(fminf(a1.x, a1.y), fminf(a1.z, a1.w)));
    float vB = fminf(fminf(fminf(b0.x, b0.y), fminf(b0.z, b0.w)),
                     fminf(fminf(b1.x, b1.y), fminf(b1.z, b1.w)));
    float sA = vA, sE = sqrtf(fmaxf(vA, 0.f)), sB = vB, sU = unc[q];

    #pragma unroll
    for (int off = 32; off > 0; off >>= 1) {
        sA += __shfl_down(sA, off);  sE += __shfl_down(sE, off);
        sB += __shfl_down(sB, off);  sU += __shfl_down(sU, off);
    }
    __shared__ float sw[4][4];
    const int lane = threadIdx.x & 63, wave = threadIdx.x >> 6;
    if (lane == 0) { sw[wave][0] = sA; sw[wave][1] = sE;
                     sw[wave][2] = sB; sw[wave][3] = sU; }
    __syncthreads();
    if (threadIdx.x < 4) {
        partials[blockIdx.x * 4 + threadIdx.x] =
            sw[0][threadIdx.x] + sw[1][threadIdx.x] +
            sw[2][threadIdx.x] + sw[3][threadIdx.x];
    }
}

__global__ void __launch_bounds__(64) finalize_kernel(
    const float* __restrict__ partials, float* __restrict__ out)
{
    const float4* p4 = (const float4*)partials;      // 128 rows of 4
    float4 s0 = p4[threadIdx.x], s1 = p4[threadIdx.x + 64];
    float sA = s0.x + s1.x, sE = s0.y + s1.y, sB = s0.z + s1.z, sU = s0.w + s1.w;
    #pragma unroll
    for (int off = 32; off > 0; off >>= 1) {
        sA += __shfl_down(sA, off);  sE += __shfl_down(sE, off);
        sB += __shfl_down(sB, off);  sU += __shfl_down(sU, off);
    }
    if (threadIdx.x == 0) {
        const float invBN = 1.0f / (float)(Bb * Nn);
        const float invBM = 1.0f / (float)(Bb * Mm);
        out[0] = (sA * invBN + sB * invBM) + 0.5f * (sE * invBN)
               + 0.01f * (sU * invBN);
    }
}

extern "C" void kernel_launch(void* const* d_in, const int* in_sizes, int n_in,
                              void* d_out, int out_size, void* d_ws, size_t ws_size,
                              hipStream_t stream) {
    const float* pred = (const float*)d_in[0];   // [8,4096,3]
    const float* targ = (const float*)d_in[1];   // [8,4096,3]
    const float* unc  = (const float*)d_in[2];   // [8,4096]
    float* out      = (float*)d_out;
    float* mins     = (float*)d_ws;                    // NQ x NE floats = 2 MB
    float* partials = (float*)d_ws + (size_t)NQ * NE;  // 128 x 4 floats

    chamfer_kernel<<<1024, BLOCK, 0, stream>>>(pred, targ, mins);
    reduce_kernel<<<128, 256, 0, stream>>>(mins, unc, partials);
    finalize_kernel<<<1, 64, 0, stream>>>(partials, out);
}

// Round 8
// 26.485 us; speedup vs baseline: 1.2664x; 1.2664x over previous
//
#include <hip/hip_runtime.h>
#include <math.h>

typedef _Float16 half8 __attribute__((ext_vector_type(8)));
typedef float    f32x4 __attribute__((ext_vector_type(4)));

#define Bb 8
#define Nn 4096
#define Mm 4096
#define BLOCK 512
#define WAVES 8
#define QB 1024              // queries per block
#define MB 512               // targets per block (one M-eighth)
#define NE 8                 // M eighths
#define NTW 8                // n-tiles per wave = (QB/16)/WAVES
#define MTILES (MB / 16)     // 32 m-tiles per block
#define NQ (2 * Bb * Nn)     // 65536 query slots (both dirs)

// d_ws layout:
//   mins[NQ][NE]     : per-query per-eighth partial min-d2 (pp already folded in)
//   partials[128][4] : per-reduce-block {chamferA, emd, chamferB, unc} sums
// Every slot rewritten every call (no memset, no atomics, deterministic).

// MFMA formulation: d2 = |p|^2 + |t|^2 - 2 p.t as ONE K=8 dot product:
//   A[n] = [x, y, z, pp_hi, 1, pp_lo, 1, 0]          (f16)
//   B[m] = [-2tx, -2ty, -2tz, 1, tt_hi, 1, tt_lo, 0] (f16)
// pp/tt computed from the f16-QUANTIZED coords and hi/lo-split, and -2*f16(t)
// is exact, so d2 == |p_q - t_q|^2 exactly (f32 accumulate); error is pure
// point quantization (~1e-4, mean-zero). One mfma_f32_16x16x32_f16 = 256 d2.
// Fragment mapping (CDNA4): A: row = lane%16, k = 8*(lane/16)+elem;
// B: col = lane%16, k = 8*(lane/16)+elem; only lanes 0-15 carry data (K=8),
// lanes 16-63 read a zero frag. C/D: col = lane&15, row = (lane>>4)*4 + reg.
__global__ void __launch_bounds__(BLOCK) chamfer_mfma_kernel(
    const float* __restrict__ pred,
    const float* __restrict__ targ,
    float* __restrict__ mins)
{
    __shared__ uint4 fragA[QB];      // 16 KB
    __shared__ uint4 fragB[MB];      // 8 KB
    __shared__ uint4 fragZ;          // zero frag for lanes >= 16

    const int tid  = threadIdx.x;
    const int lane = tid & 63;
    const int wave = tid >> 6;

    const int id     = blockIdx.x;
    const int eighth = id & 7;
    const int qg     = (id >> 3) & 3;
    const int b      = (id >> 5) & 7;
    const int dir    = id >> 8;

    const float* Q = dir ? targ : pred;
    const float* T = dir ? pred : targ;

    // ---- stage A frags (2 queries/thread) ----
    for (int s = tid; s < QB; s += BLOCK) {
        const float* g = Q + ((size_t)b * Nn + qg * QB + s) * 3;
        _Float16 xh = (_Float16)g[0], yh = (_Float16)g[1], zh = (_Float16)g[2];
        float xq = (float)xh, yq = (float)yh, zq = (float)zh;
        float pp = fmaf(xq, xq, fmaf(yq, yq, zq * zq));
        _Float16 ph = (_Float16)pp;
        _Float16 pl = (_Float16)(pp - (float)ph);
        half8 h;
        h[0] = xh; h[1] = yh; h[2] = zh; h[3] = ph;
        h[4] = (_Float16)1.0f; h[5] = pl; h[6] = (_Float16)1.0f; h[7] = (_Float16)0.0f;
        fragA[s] = *reinterpret_cast<uint4*>(&h);
    }
    // ---- stage B frags (1 target/thread) ----
    {
        const float* g = T + ((size_t)b * Mm + eighth * MB + tid) * 3;
        _Float16 xh = (_Float16)g[0], yh = (_Float16)g[1], zh = (_Float16)g[2];
        float xq = (float)xh, yq = (float)yh, zq = (float)zh;
        float tt = fmaf(xq, xq, fmaf(yq, yq, zq * zq));
        _Float16 th = (_Float16)tt;
        _Float16 tl = (_Float16)(tt - (float)th);
        const _Float16 m2 = (_Float16)(-2.0f);
        half8 h;
        h[0] = m2 * xh; h[1] = m2 * yh; h[2] = m2 * zh; h[3] = (_Float16)1.0f;
        h[4] = th; h[5] = (_Float16)1.0f; h[6] = tl; h[7] = (_Float16)0.0f;
        fragB[tid] = *reinterpret_cast<uint4*>(&h);
    }
    if (tid == 0) fragZ = make_uint4(0u, 0u, 0u, 0u);
    __syncthreads();

    // ---- per-lane frag addresses (lanes >= 16 read the zero frag) ----
    const bool lo16 = (lane < 16);
    const uint4* aBase = lo16 ? &fragA[wave * NTW * 16 + lane] : &fragZ;
    const int    aStep = lo16 ? 16 : 0;
    const uint4* bBase = lo16 ? &fragB[lane] : &fragZ;
    const int    bStep = lo16 ? 16 : 0;

    half8 a[NTW];
    #pragma unroll
    for (int t = 0; t < NTW; ++t)
        a[t] = *reinterpret_cast<const half8*>(aBase + t * aStep);

    f32x4 acc[NTW];
    #pragma unroll
    for (int t = 0; t < NTW; ++t) {
        acc[t][0] = __builtin_inff(); acc[t][1] = __builtin_inff();
        acc[t][2] = __builtin_inff(); acc[t][3] = __builtin_inff();
    }

    // ---- main loop: 2 m-tiles/iter; 16 MFMA + 32 v_min3, pipes overlap ----
    const f32x4 cz = {0.f, 0.f, 0.f, 0.f};
    for (int j = 0; j < MTILES; j += 2) {
        half8 b0 = *reinterpret_cast<const half8*>(bBase + j * bStep);
        half8 b1 = *reinterpret_cast<const half8*>(bBase + (j + 1) * bStep);
        #pragma unroll
        for (int t = 0; t < NTW; ++t) {
            f32x4 c = __builtin_amdgcn_mfma_f32_16x16x32_f16(a[t], b0, cz, 0, 0, 0);
            f32x4 d = __builtin_amdgcn_mfma_f32_16x16x32_f16(a[t], b1, cz, 0, 0, 0);
            #pragma unroll
            for (int k = 0; k < 4; ++k)
                acc[t][k] = fminf(fminf(acc[t][k], c[k]), d[k]);   // v_min3
        }
    }

    // ---- epilogue: row-min across the 16 cols (xor-shuffle), then store ----
    #pragma unroll
    for (int t = 0; t < NTW; ++t) {
        f32x4 v = acc[t];
        #pragma unroll
        for (int m = 1; m < 16; m <<= 1) {
            #pragma unroll
            for (int k = 0; k < 4; ++k)
                v[k] = fminf(v[k], __shfl_xor(v[k], m));
        }
        if ((lane & 15) == 0) {          // lanes 0,16,32,48: rowgroups 0..3
            const int rowbase = (lane >> 4) * 4;
            const int nloc = (wave * NTW + t) * 16 + rowbase;
            const size_t qs = ((size_t)dir * Bb + b) * Nn + qg * QB + nloc;
            #pragma unroll
            for (int k = 0; k < 4; ++k)
                mins[(qs + k) * NE + eighth] = v[k];
        }
    }
}

// 128 blocks x 256 thr: min over NE eighths, per-block partial sums (no atomics)
__global__ void __launch_bounds__(256) reduce_kernel(
    const float* __restrict__ mins, const float* __restrict__ unc,
    float* __restrict__ partials)
{
    const int q = blockIdx.x * 256 + threadIdx.x;    // [0, 32768)
    const float4* m4 = (const float4*)mins;          // 2 float4 per query

    float4 a0 = m4[2 * q],           a1 = m4[2 * q + 1];
    float4 b0 = m4[2 * (q + 32768)], b1 = m4[2 * (q + 32768) + 1];
    float vA = fminf(fminf(fminf(a0.x, a0.y), fminf(a0.z, a0.w)),
                     fminf(fminf(a1.x, a1.y), fminf(a1.z, a1.w)));
    float vB = fminf(fminf(fminf(b0.x, b0.y), fminf(b0.z, b0.w)),
                     fminf(fminf(b1.x, b1.y), fminf(b1.z, b1.w)));
    float sA = vA, sE = sqrtf(fmaxf(vA, 0.f)), sB = vB, sU = unc[q];

    #pragma unroll
    for (int off = 32; off > 0; off >>= 1) {
        sA += __shfl_down(sA, off);  sE += __shfl_down(sE, off);
        sB += __shfl_down(sB, off);  sU += __shfl_down(sU, off);
    }
    __shared__ float sw[4][4];
    const int lane = threadIdx.x & 63, wave = threadIdx.x >> 6;
    if (lane == 0) { sw[wave][0] = sA; sw[wave][1] = sE;
                     sw[wave][2] = sB; sw[wave][3] = sU; }
    __syncthreads();
    if (threadIdx.x < 4) {
        partials[blockIdx.x * 4 + threadIdx.x] =
            sw[0][threadIdx.x] + sw[1][threadIdx.x] +
            sw[2][threadIdx.x] + sw[3][threadIdx.x];
    }
}

__global__ void __launch_bounds__(64) finalize_kernel(
    const float* __restrict__ partials, float* __restrict__ out)
{
    const float4* p4 = (const float4*)partials;      // 128 rows of 4
    float4 s0 = p4[threadIdx.x], s1 = p4[threadIdx.x + 64];
    float sA = s0.x + s1.x, sE = s0.y + s1.y, sB = s0.z + s1.z, sU = s0.w + s1.w;
    #pragma unroll
    for (int off = 32; off > 0; off >>= 1) {
        sA += __shfl_down(sA, off);  sE += __shfl_down(sE, off);
        sB += __shfl_down(sB, off);  sU += __shfl_down(sU, off);
    }
    if (threadIdx.x == 0) {
        const float invBN = 1.0f / (float)(Bb * Nn);
        const float invBM = 1.0f / (float)(Bb * Mm);
        out[0] = (sA * invBN + sB * invBM) + 0.5f * (sE * invBN)
               + 0.01f * (sU * invBN);
    }
}

extern "C" void kernel_launch(void* const* d_in, const int* in_sizes, int n_in,
                              void* d_out, int out_size, void* d_ws, size_t ws_size,
                              hipStream_t stream) {
    const float* pred = (const float*)d_in[0];   // [8,4096,3]
    const float* targ = (const float*)d_in[1];   // [8,4096,3]
    const float* unc  = (const float*)d_in[2];   // [8,4096]
    float* out      = (float*)d_out;
    float* mins     = (float*)d_ws;                    // NQ x NE floats = 2 MB
    float* partials = (float*)d_ws + (size_t)NQ * NE;  // 128 x 4 floats

    // 2 dirs x 8 batches x 4 q-groups x 8 eighths = 512 blocks of 512 thr
    chamfer_mfma_kernel<<<512, BLOCK, 0, stream>>>(pred, targ, mins);
    reduce_kernel<<<128, 256, 0, stream>>>(mins, unc, partials);
    finalize_kernel<<<1, 64, 0, stream>>>(partials, out);
}

// Round 9
// 26.350 us; speedup vs baseline: 1.2729x; 1.0051x over previous
//
#include <hip/hip_runtime.h>
#include <math.h>

typedef _Float16 half8 __attribute__((ext_vector_type(8)));
typedef float    f32x4 __attribute__((ext_vector_type(4)));

#define Bb 8
#define Nn 4096
#define Mm 4096
#define BLOCK 512
#define WAVES 8
#define QB 256               // queries per block
#define NTW 2                // n-tiles per wave = (QB/16)/WAVES
#define MTILES (Mm / 16)     // 256 m-tiles (full M per block)
#define GRID 256             // 2 dirs x 8 batches x 16 qtiles

// d_ws layout:
//   psum[GRID] float4 : per-block {sum_min (chamfer), sum_sqrt(min) (emd), sum_unc, 0}
//                       every slot rewritten every call (no memset needed)
//   counter (u32)     : at byte offset 4096; never reset — last-block detection is
//                       modular ((old+1)%GRID==0 fires exactly once per launch from
//                       ANY starting value, so 0xAAAAAAAA poison is harmless)
//
// MFMA formulation (validated in round 8): d2 = |p|^2+|t|^2-2p.t as one K=8 dot:
//   A[n] = [x, y, z, pp_hi, 1, pp_lo, 1, 0]           (f16, lanes 0-15 carry k=0..7)
//   B[m] = [-2tx, -2ty, -2tz, 1, tt_hi, 1, tt_lo, 0]  (f16)
// Lanes 16-63 hold ZERO A-frags, so their B reads are don't-care -> all lanes read
// fragB[(lane&15)] (broadcast). C/D: col = lane&15, row = (lane>>4)*4 + reg.
__global__ void __launch_bounds__(BLOCK) chamfer_fused_kernel(
    const float* __restrict__ pred,
    const float* __restrict__ targ,
    const float* __restrict__ unc,
    float4* __restrict__ psum,
    unsigned* __restrict__ counter,
    float* __restrict__ out)
{
    __shared__ uint4 fragB[Mm];          // exactly 64 KB; overlaid as wsum after use
    float* wsum = (float*)fragB;         // floats [0..31]: 8 waves x 4; [32]: isLast

    const int tid  = threadIdx.x;
    const int lane = tid & 63;
    const int wave = tid >> 6;

    const int id  = blockIdx.x;
    const int qt  = id & 15;
    const int b   = (id >> 4) & 7;
    const int dir = id >> 7;

    const float* Q = dir ? targ : pred;
    const float* T = dir ? pred : targ;

    // ---- uncertainty slice: 128 floats per block (wave 0, lanes 0-31) ----
    float su = 0.f;
    if (tid < 32) {
        float4 uu = ((const float4*)unc)[id * 32 + tid];
        su = (uu.x + uu.y) + (uu.z + uu.w);
    }

    // ---- stage all Mm B-frags into LDS (8 per thread) ----
    for (int s = tid; s < Mm; s += BLOCK) {
        const float* g = T + ((size_t)b * Mm + s) * 3;
        _Float16 xh = (_Float16)g[0], yh = (_Float16)g[1], zh = (_Float16)g[2];
        float xq = (float)xh, yq = (float)yh, zq = (float)zh;
        float tt = fmaf(xq, xq, fmaf(yq, yq, zq * zq));
        _Float16 th = (_Float16)tt;
        _Float16 tl = (_Float16)(tt - (float)th);
        const _Float16 m2 = (_Float16)(-2.0f);
        half8 h;
        h[0] = m2 * xh; h[1] = m2 * yh; h[2] = m2 * zh; h[3] = (_Float16)1.0f;
        h[4] = th; h[5] = (_Float16)1.0f; h[6] = tl; h[7] = (_Float16)0.0f;
        fragB[s] = *reinterpret_cast<uint4*>(&h);
    }

    // ---- A-frags in registers: lanes 0-15 load their query from global ----
    const bool lo16 = (lane < 16);
    half8 a[NTW];
    #pragma unroll
    for (int t = 0; t < NTW; ++t) {
        half8 h;
        #pragma unroll
        for (int e = 0; e < 8; ++e) h[e] = (_Float16)0.0f;
        if (lo16) {
            const int n = qt * QB + (wave * NTW + t) * 16 + lane;
            const float* g = Q + ((size_t)b * Nn + n) * 3;
            _Float16 xh = (_Float16)g[0], yh = (_Float16)g[1], zh = (_Float16)g[2];
            float xq = (float)xh, yq = (float)yh, zq = (float)zh;
            float pp = fmaf(xq, xq, fmaf(yq, yq, zq * zq));
            _Float16 ph = (_Float16)pp;
            _Float16 pl = (_Float16)(pp - (float)ph);
            h[0] = xh; h[1] = yh; h[2] = zh; h[3] = ph;
            h[4] = (_Float16)1.0f; h[5] = pl; h[6] = (_Float16)1.0f; h[7] = (_Float16)0.0f;
        }
        a[t] = h;
    }
    __syncthreads();

    // ---- main loop over all 256 m-tiles: 4 MFMA + 8 v_min3 per 2 tiles ----
    const int col = lane & 15;
    const f32x4 cz = {0.f, 0.f, 0.f, 0.f};
    const float inf = __builtin_inff();
    f32x4 acc0 = {inf, inf, inf, inf}, acc1 = acc0;
    #pragma unroll 4
    for (int j = 0; j < MTILES; j += 2) {
        half8 b0 = *reinterpret_cast<const half8*>(&fragB[(j << 4) + col]);
        half8 b1 = *reinterpret_cast<const half8*>(&fragB[((j + 1) << 4) + col]);
        f32x4 c00 = __builtin_amdgcn_mfma_f32_16x16x32_f16(a[0], b0, cz, 0, 0, 0);
        f32x4 c01 = __builtin_amdgcn_mfma_f32_16x16x32_f16(a[0], b1, cz, 0, 0, 0);
        f32x4 c10 = __builtin_amdgcn_mfma_f32_16x16x32_f16(a[1], b0, cz, 0, 0, 0);
        f32x4 c11 = __builtin_amdgcn_mfma_f32_16x16x32_f16(a[1], b1, cz, 0, 0, 0);
        #pragma unroll
        for (int k = 0; k < 4; ++k) {
            acc0[k] = fminf(fminf(acc0[k], c00[k]), c01[k]);   // v_min3
            acc1[k] = fminf(fminf(acc1[k], c10[k]), c11[k]);
        }
    }

    // ---- per-wave: col-min via xor-shuffles, then chamfer/emd partial sums ----
    float s1 = 0.f, s2 = 0.f;
    #pragma unroll
    for (int t = 0; t < NTW; ++t) {
        f32x4 v = t ? acc1 : acc0;
        #pragma unroll
        for (int m = 1; m < 16; m <<= 1) {
            #pragma unroll
            for (int k = 0; k < 4; ++k)
                v[k] = fminf(v[k], __shfl_xor(v[k], m));
        }
        if (col == 0) {                 // lanes 0,16,32,48 each own 4 query rows
            #pragma unroll
            for (int k = 0; k < 4; ++k) {
                const float d2 = v[k];
                s1 += d2;
                s2 += sqrtf(fmaxf(d2, 0.f));
            }
        }
    }
    #pragma unroll
    for (int m = 1; m < 64; m <<= 1) {  // wave-wide sums (zeros elsewhere)
        s1 += __shfl_xor(s1, m);
        s2 += __shfl_xor(s2, m);
        su += __shfl_xor(su, m);
    }

    // ---- block reduce via LDS overlay, publish psum, last-block finalize ----
    __syncthreads();                    // all fragB reads done -> overlay safe
    if (lane == 0) {
        wsum[wave * 4 + 0] = s1;
        wsum[wave * 4 + 1] = s2;
        wsum[wave * 4 + 2] = su;
    }
    __syncthreads();
    if (tid == 0) {
        float S1 = 0.f, S2 = 0.f, SU = 0.f;
        #pragma unroll
        for (int w = 0; w < WAVES; ++w) {
            S1 += wsum[w * 4 + 0]; S2 += wsum[w * 4 + 1]; SU += wsum[w * 4 + 2];
        }
        psum[id] = make_float4(S1, S2, SU, 0.f);
        __threadfence();                             // release psum
        unsigned old = atomicAdd(counter, 1u);       // device-scope
        ((int*)wsum)[32] = (((old + 1) & (GRID - 1)) == 0) ? 1 : 0;
    }
    __syncthreads();
    if (((int*)wsum)[32]) {
        __threadfence();                             // acquire psum
        float sa = 0.f, sb = 0.f, se = 0.f, sU = 0.f;
        if (tid < GRID) {
            float4 v = psum[tid];
            if (tid < GRID / 2) { sa = v.x; se = v.y; }
            else                { sb = v.x; }
            sU = v.z;
        }
        #pragma unroll
        for (int m = 1; m < 64; m <<= 1) {
            sa += __shfl_xor(sa, m); sb += __shfl_xor(sb, m);
            se += __shfl_xor(se, m); sU += __shfl_xor(sU, m);
        }
        __syncthreads();
        if (lane == 0) {
            wsum[wave * 4 + 0] = sa; wsum[wave * 4 + 1] = sb;
            wsum[wave * 4 + 2] = se; wsum[wave * 4 + 3] = sU;
        }
        __syncthreads();
        if (tid == 0) {
            float SA = 0.f, SB = 0.f, SE = 0.f, SU2 = 0.f;
            #pragma unroll
            for (int w = 0; w < WAVES; ++w) {
                SA += wsum[w * 4 + 0]; SB += wsum[w * 4 + 1];
                SE += wsum[w * 4 + 2]; SU2 += wsum[w * 4 + 3];
            }
            const float invBN = 1.0f / (float)(Bb * Nn);
            const float invBM = 1.0f / (float)(Bb * Mm);
            out[0] = (SA * invBN + SB * invBM) + 0.5f * (SE * invBN)
                   + 0.01f * (SU2 * invBN);
        }
    }
}

extern "C" void kernel_launch(void* const* d_in, const int* in_sizes, int n_in,
                              void* d_out, int out_size, void* d_ws, size_t ws_size,
                              hipStream_t stream) {
    const float* pred = (const float*)d_in[0];   // [8,4096,3]
    const float* targ = (const float*)d_in[1];   // [8,4096,3]
    const float* unc  = (const float*)d_in[2];   // [8,4096]
    float* out = (float*)d_out;

    float4*   psum    = (float4*)d_ws;                        // 256 x 16 B
    unsigned* counter = (unsigned*)((char*)d_ws + 4096);      // never reset

    chamfer_fused_kernel<<<GRID, BLOCK, 0, stream>>>(pred, targ, unc,
                                                     psum, counter, out);
}